// Round 1
// baseline (441.834 us; speedup 1.0000x reference)
//
#include <hip/hip_runtime.h>
#include <stdint.h>

typedef __attribute__((ext_vector_type(8))) short short8;
typedef __attribute__((ext_vector_type(4))) float f32x4;

#define N_IMG 32
#define C_IN  256
#define HH    64
#define WW    64
#define O_OUT 256
#define HP    66
#define WP    66

#define QX_ELEMS (N_IMG*HP*WP*C_IN)      // 35,684,352
#define QX_BYTES ((size_t)QX_ELEMS*2)    // 71,368,704
#define QW_ELEMS (9*O_OUT*C_IN)          // 589,824
#define QW_BYTES ((size_t)QW_ELEMS*2)

// ---------- quantization helpers (match jnp reference bit-for-bit) ----------

// nearest E2M1 magnitude; ties round up (jnp.digitize right=False: a==mid -> upper)
__device__ __forceinline__ float e2m1_mag(float a) {
    return a < 0.25f ? 0.0f
         : a < 0.75f ? 0.5f
         : a < 1.25f ? 1.0f
         : a < 1.75f ? 1.5f
         : a < 2.5f  ? 2.0f
         : a < 3.5f  ? 3.0f
         : a < 5.0f  ? 4.0f : 6.0f;
}

// scale = 2^ceil(log2(max(amax,1e-30)/6)), or 1.0 if amax==0.
// frexp: ac = m*2^e, m in [0.5,1). ceil(e + log2(m/6)) = e-2 if m>0.75 else e-3
// (exact at the amax = 6*2^k boundaries, where log2 is an exact integer).
__device__ __forceinline__ float blk_scale(float amax) {
    float ac = fmaxf(amax, 1e-30f);
    int e;
    float m = frexpf(ac, &e);
    int ex = (m > 0.75f) ? (e - 2) : (e - 3);
    float s = ldexpf(1.0f, ex);
    return (amax > 0.0f) ? s : 1.0f;
}

// values are E2M1-grid * pow2 -> <=3 significand bits -> exact in bf16 (truncate == round)
__device__ __forceinline__ unsigned short to_bf16_bits(float v) {
    union { float f; unsigned int u; } cv; cv.f = v;
    return (unsigned short)(cv.u >> 16);
}

// ---------- x: fp32 NCHW -> exact-bf16 NHWC with +1 spatial halo ----------
// grid: N*H*(C/64) = 8192 blocks, 256 threads. Each thread = one quant block of 16 (along W).
__global__ __launch_bounds__(256) void quant_x_kernel(const float* __restrict__ x,
                                                      unsigned short* __restrict__ qx) {
    int bid = blockIdx.x;
    int n  = bid >> 8;          // / (64*4)
    int h  = (bid >> 2) & 63;
    int cb = bid & 3;           // 64-channel group
    int t  = threadIdx.x;
    int c_local = t >> 2;       // 0..63
    int wb = t & 3;             // 16-wide W block

    const float* src = x + ((((size_t)(n*C_IN + cb*64 + c_local))*HH + h)*WW + wb*16);
    float v[16];
#pragma unroll
    for (int j = 0; j < 4; ++j) {
        float4 f = ((const float4*)src)[j];
        v[j*4+0]=f.x; v[j*4+1]=f.y; v[j*4+2]=f.z; v[j*4+3]=f.w;
    }
    float amax = 0.f;
#pragma unroll
    for (int j = 0; j < 16; ++j) amax = fmaxf(amax, fabsf(v[j]));
    float s = blk_scale(amax);
    float inv = 1.0f / s;       // pow2 -> exact

    __shared__ unsigned short lds[64][64];   // [w][c_local]
#pragma unroll
    for (int j = 0; j < 16; ++j) {
        float q = e2m1_mag(fabsf(v[j]) * inv) * s;
        q = copysignf(q, v[j]);
        lds[wb*16 + j][c_local] = to_bf16_bits(q);
    }
    __syncthreads();
    // coalesced NHWC write: thread t writes 16 channels of one w
    int w  = t >> 2;
    int cg = (t & 3) * 16;
    unsigned short* dst = qx + ((((size_t)(n*HP + (h+1)))*WP + (w+1))*C_IN + cb*64 + cg);
    *(uint4*)(dst)     = *(const uint4*)&lds[w][cg];
    *(uint4*)(dst + 8) = *(const uint4*)&lds[w][cg + 8];
}

// ---------- w: fp32 OIHW flat-16 blocks -> exact-bf16 [kpos][O][C] ----------
// 36864 blocks of 16; grid 144 x 256 threads, one quant block per thread.
__global__ __launch_bounds__(256) void quant_w_kernel(const float* __restrict__ w,
                                                      unsigned short* __restrict__ qw) {
    int b = blockIdx.x * 256 + threadIdx.x;
    const float* src = w + (size_t)b * 16;
    float v[16];
#pragma unroll
    for (int j = 0; j < 4; ++j) {
        float4 f = ((const float4*)src)[j];
        v[j*4+0]=f.x; v[j*4+1]=f.y; v[j*4+2]=f.z; v[j*4+3]=f.w;
    }
    float amax = 0.f;
#pragma unroll
    for (int j = 0; j < 16; ++j) amax = fmaxf(amax, fabsf(v[j]));
    float s = blk_scale(amax);
    float inv = 1.0f / s;
#pragma unroll
    for (int j = 0; j < 16; ++j) {
        float q = copysignf(e2m1_mag(fabsf(v[j]) * inv) * s, v[j]);
        int f = b*16 + j;           // flat OIHW index
        int o = f / 2304;           // 2304 = 256*9 per o (divisible by 16)
        int r = f - o*2304;
        int ci = r / 9;
        int p  = r - ci*9;          // kh*3+kw
        qw[((size_t)(p*O_OUT + o))*C_IN + ci] = to_bf16_bits(q);
    }
}

// ---------- conv: implicit GEMM, A=weights(M=O=128/block), B=pixels(N=128/block) ----------
__device__ __forceinline__ void gld16(void* lds, const void* g) {
    __builtin_amdgcn_global_load_lds(
        (const __attribute__((address_space(1))) unsigned int*)g,
        (__attribute__((address_space(3))) unsigned int*)lds,
        16, 0, 0);
}

__global__ __launch_bounds__(256) void conv_kernel(const unsigned short* __restrict__ qw,
                                                   const unsigned short* __restrict__ qx,
                                                   float* __restrict__ out) {
    __shared__ unsigned short Wt[128][32];   // [o][k]   A operand rows
    __shared__ unsigned short Xt[128][32];   // [pix][k] B operand rows

    const int tid  = threadIdx.x;
    const int wave = tid >> 6;
    const int lane = tid & 63;
    const int lo16 = lane & 15;
    const int quad = lane >> 4;

    const int bx  = blockIdx.x;          // 0..1023  (pixel tiles of 128)
    const int o0  = blockIdx.y * 128;    // 0 or 128
    const int n   = bx >> 5;             // 32 blocks per image (4096 px / 128)
    const int hw0 = (bx & 31) * 128;     // flat h*64+w base within image
    const int h0  = hw0 >> 6;

    // staging geometry: wave handles slots {2w,2w+1} of both tiles; 1 KB (16 rows) per slot
    const int s0 = wave * 2;
    const int r0 = s0 * 16 + (lane >> 2);
    const int r1 = r0 + 16;
    const int co = (lane & 3) * 8;       // bf16 elems; 16B per lane

    const unsigned short* wb0 = qw + (size_t)(o0 + r0) * C_IN + co;
    const unsigned short* wb1 = qw + (size_t)(o0 + r1) * C_IN + co;

    auto xbase = [&](int r) -> const unsigned short* {
        int h = h0 + (r >> 6);
        int w = r & 63;
        return qx + (((size_t)(n*HP + h + 1))*WP + (w + 1))*C_IN + co;
    };
    const unsigned short* xb0 = xbase(r0);
    const unsigned short* xb1 = xbase(r1);

    unsigned short* ldsA0 = &Wt[s0*16][0];
    unsigned short* ldsA1 = &Wt[s0*16 + 16][0];
    unsigned short* ldsB0 = &Xt[s0*16][0];
    unsigned short* ldsB1 = &Xt[s0*16 + 16][0];

    const int wmo = (wave & 1) * 64;     // wave's o sub-tile
    const int wnp = (wave >> 1) * 64;    // wave's pixel sub-tile

    f32x4 acc[4][4];
#pragma unroll
    for (int i = 0; i < 4; ++i)
#pragma unroll
        for (int j = 0; j < 4; ++j)
            acc[i][j] = (f32x4){0.f, 0.f, 0.f, 0.f};

    for (int p = 0; p < 9; ++p) {
        const int dh = p/3 - 1, dw = p%3 - 1;
        const int xoff = (dh*WP + dw) * C_IN;   // halo shift (always in-bounds of padded qx)
        const int woff = p * (O_OUT * C_IN);
        for (int cc = 0; cc < 8; ++cc) {
            const int c0 = cc * 32;
            gld16(ldsA0, wb0 + woff + c0);
            gld16(ldsA1, wb1 + woff + c0);
            gld16(ldsB0, xb0 + xoff + c0);
            gld16(ldsB1, xb1 + xoff + c0);
            __syncthreads();

            short8 af[4], bf_[4];
#pragma unroll
            for (int i = 0; i < 4; ++i)
                af[i] = *(const short8*)&Wt[wmo + i*16 + lo16][quad*8];
#pragma unroll
            for (int j = 0; j < 4; ++j)
                bf_[j] = *(const short8*)&Xt[wnp + j*16 + lo16][quad*8];
#pragma unroll
            for (int i = 0; i < 4; ++i)
#pragma unroll
                for (int j = 0; j < 4; ++j)
                    acc[i][j] = __builtin_amdgcn_mfma_f32_16x16x32_bf16(
                        af[i], bf_[j], acc[i][j], 0, 0, 0);
            __syncthreads();
        }
    }

    // epilogue: D row (quad*4+r) = o, D col (lane&15) = pixel -> contiguous stores over pixels
#pragma unroll
    for (int i = 0; i < 4; ++i) {
#pragma unroll
        for (int j = 0; j < 4; ++j) {
            int o  = o0 + wmo + i*16 + quad*4;
            int pl = wnp + j*16 + lo16;
            size_t base = ((size_t)(n*O_OUT + o))*(HH*WW) + hw0 + pl;
#pragma unroll
            for (int r = 0; r < 4; ++r)
                out[base + (size_t)r*(HH*WW)] = acc[i][j][r];
        }
    }
}

extern "C" void kernel_launch(void* const* d_in, const int* in_sizes, int n_in,
                              void* d_out, int out_size, void* d_ws, size_t ws_size,
                              hipStream_t stream) {
    const float* x = (const float*)d_in[0];
    const float* w = (const float*)d_in[1];
    float* out = (float*)d_out;

    unsigned short* qx = (unsigned short*)d_ws;                       // padded NHWC bf16
    unsigned short* qw = (unsigned short*)((char*)d_ws + QX_BYTES);   // [9][O][C] bf16

    // zero halo (and interior, overwritten below) — ws is re-poisoned before every launch
    hipMemsetAsync(qx, 0, QX_BYTES, stream);
    quant_x_kernel<<<dim3(N_IMG*HH*4), 256, 0, stream>>>(x, qx);
    quant_w_kernel<<<dim3(QW_ELEMS/16/256), 256, 0, stream>>>(w, qw);
    conv_kernel<<<dim3(1024, 2), 256, 0, stream>>>(qw, qx, out);
}

// Round 2
// 433.383 us; speedup vs baseline: 1.0195x; 1.0195x over previous
//
#include <hip/hip_runtime.h>
#include <stdint.h>

typedef __attribute__((ext_vector_type(8))) short short8;
typedef __attribute__((ext_vector_type(4))) float f32x4;

#define N_IMG 32
#define C_IN  256
#define HH    64
#define WW    64
#define O_OUT 256
#define HP    66
#define WP    66

#define QX_ELEMS (N_IMG*HP*WP*C_IN)      // 35,684,352
#define QX_BYTES ((size_t)QX_ELEMS*2)    // 71,368,704
#define QW_ELEMS (9*O_OUT*C_IN)          // 589,824

// ---------- quantization helpers (match jnp reference bit-for-bit) ----------

// nearest E2M1 magnitude; ties round up (jnp.digitize right=False: a==mid -> upper)
__device__ __forceinline__ float e2m1_mag(float a) {
    return a < 0.25f ? 0.0f
         : a < 0.75f ? 0.5f
         : a < 1.25f ? 1.0f
         : a < 1.75f ? 1.5f
         : a < 2.5f  ? 2.0f
         : a < 3.5f  ? 3.0f
         : a < 5.0f  ? 4.0f : 6.0f;
}

// scale = 2^ceil(log2(max(amax,1e-30)/6)), or 1.0 if amax==0; also exact 1/scale.
__device__ __forceinline__ void blk_scale2(float amax, float& s, float& inv) {
    float ac = fmaxf(amax, 1e-30f);
    int e;
    float m = frexpf(ac, &e);
    int ex = (m > 0.75f) ? (e - 2) : (e - 3);
    if (amax > 0.0f) { s = ldexpf(1.0f, ex); inv = ldexpf(1.0f, -ex); }
    else             { s = 1.0f; inv = 1.0f; }
}

// E2M1-grid * pow2 -> 1 mantissa bit -> exact in bf16 (truncate == round)
__device__ __forceinline__ unsigned short to_bf16_bits(float v) {
    union { float f; unsigned int u; } cv; cv.f = v;
    return (unsigned short)(cv.u >> 16);
}

// ---------- halo zero: only the 4.3 MB border of qx (replaces 71 MB memset) ----------
// Region A: h in {0,65}, all (w,c): 32*2*2112 uint4 = 135168
// Region B: h in 1..64, w in {0,65}: 32*4096 uint4 = 131072 ; total 266240 = 1040*256
__global__ __launch_bounds__(256) void halo_zero_kernel(unsigned short* __restrict__ qx) {
    int id = blockIdx.x * 256 + threadIdx.x;
    size_t off;
    if (id < 135168) {
        int n = id / 4224, r = id % 4224;
        int h = (r / 2112) * 65;
        int k = r % 2112;
        off = (((size_t)(n*HP + h)) * WP) * C_IN + (size_t)k * 8;
    } else {
        int j = id - 135168;
        int n = j >> 12, r = j & 4095;
        int h = 1 + (r >> 6);
        int w = ((r >> 5) & 1) * 65;
        int k = r & 31;
        off = (((size_t)(n*HP + h)) * WP + w) * C_IN + (size_t)k * 8;
    }
    uint4 z; z.x = z.y = z.z = z.w = 0u;
    *(uint4*)(qx + off) = z;
}

// ---------- x: fp32 NCHW -> exact-bf16 NHWC(+halo) ----------
// Block = (n, h, 64-channel group). Phase 1: coalesced 256B-row loads into padded
// fp32 LDS. Phase 2a: per-(c,16w)-block scales. Phase 2b: transposed quantize +
// vectorized NHWC store. All LDS access patterns <=2-way (free).
__global__ __launch_bounds__(256) void quant_x_kernel(const float* __restrict__ x,
                                                      unsigned short* __restrict__ qx) {
    __shared__ float xf[64][65];     // [c_local][w], pad 1 -> transpose reads 2-way
    __shared__ float sarr[4][65];    // [wb][c_local] scale
    __shared__ float iarr[4][65];    // [wb][c_local] 1/scale (exact pow2)

    const int bid = blockIdx.x;
    const int n  = bid >> 8;
    const int h  = (bid >> 2) & 63;
    const int cb = bid & 3;
    const int t  = threadIdx.x;

    // phase 1: global float4 loads, 16 lanes = 256B contiguous per channel row
    {
        const int rb = t >> 4;            // 0..15
        const int w4 = (t & 15) * 4;
        const float* src = x + (((size_t)(n*C_IN + cb*64)) * HH + h) * WW;
#pragma unroll
        for (int it = 0; it < 4; ++it) {
            int r = it * 16 + rb;
            float4 g = *(const float4*)(src + (size_t)r * (HH*WW) + w4);
            xf[r][w4+0] = g.x; xf[r][w4+1] = g.y; xf[r][w4+2] = g.z; xf[r][w4+3] = g.w;
        }
    }
    __syncthreads();

    // phase 2a: one quant block (c, 16 w's) per thread -> scale + inverse
    {
        const int c = t >> 2, wb = t & 3;
        float amax = 0.f;
#pragma unroll
        for (int j = 0; j < 16; ++j) amax = fmaxf(amax, fabsf(xf[c][wb*16 + j]));
        float s, inv;
        blk_scale2(amax, s, inv);
        sarr[wb][c] = s;
        iarr[wb][c] = inv;
    }
    __syncthreads();

    // phase 2b: thread owns (w, 16 channels) -> NHWC-contiguous 32B store
    {
        const int w = t >> 2, cg = (t & 3) * 16, wb = w >> 4;
        unsigned short outv[16];
#pragma unroll
        for (int i = 0; i < 16; ++i) {
            int c = cg + i;
            float v = xf[c][w];
            float q = copysignf(e2m1_mag(fabsf(v) * iarr[wb][c]) * sarr[wb][c], v);
            outv[i] = to_bf16_bits(q);
        }
        unsigned short* dst = qx + (((size_t)(n*HP + h + 1)) * WP + (w + 1)) * C_IN + cb*64 + cg;
        *(uint4*)(dst)     = *(const uint4*)&outv[0];
        *(uint4*)(dst + 8) = *(const uint4*)&outv[8];
    }
}

// ---------- w: fp32 OIHW -> exact-bf16 [kpos][O][C], one block per o ----------
__global__ __launch_bounds__(256) void quant_w_kernel(const float* __restrict__ w,
                                                      unsigned short* __restrict__ qw) {
    __shared__ unsigned short lq[2304];   // one o-row, flat (ci*9 + p) order
    const int o = blockIdx.x;
    const int t = threadIdx.x;
    const float* src = w + (size_t)o * 2304;
    if (t < 144) {                        // 144 quant blocks of 16 per o
        float v[16];
#pragma unroll
        for (int j = 0; j < 4; ++j) {
            float4 f = ((const float4*)(src + t*16))[j];
            v[j*4+0]=f.x; v[j*4+1]=f.y; v[j*4+2]=f.z; v[j*4+3]=f.w;
        }
        float amax = 0.f;
#pragma unroll
        for (int j = 0; j < 16; ++j) amax = fmaxf(amax, fabsf(v[j]));
        float s, inv;
        blk_scale2(amax, s, inv);
#pragma unroll
        for (int j = 0; j < 16; ++j)
            lq[t*16 + j] = to_bf16_bits(copysignf(e2m1_mag(fabsf(v[j]) * inv) * s, v[j]));
    }
    __syncthreads();
    // scatter: thread t = ci; 9 coalesced 2B writes (one per kpos plane)
#pragma unroll
    for (int p = 0; p < 9; ++p)
        qw[((size_t)(p*O_OUT + o)) * C_IN + t] = lq[t*9 + p];
}

// ---------- conv: implicit GEMM, A=weights (O), B=pixels; 128x128 tile, BK=32 ----------
__device__ __forceinline__ void gld16(void* lds, const void* g) {
    __builtin_amdgcn_global_load_lds(
        (const __attribute__((address_space(1))) unsigned int*)g,
        (__attribute__((address_space(3))) unsigned int*)lds,
        16, 0, 0);
}

__global__ __launch_bounds__(256) void conv_kernel(const unsigned short* __restrict__ qw,
                                                   const unsigned short* __restrict__ qx,
                                                   float* __restrict__ out) {
    __shared__ unsigned short Wt[128][32];   // [o][k]
    __shared__ unsigned short Xt[128][32];   // [pix][k]

    const int tid  = threadIdx.x;
    const int wave = tid >> 6;
    const int lane = tid & 63;
    const int lo16 = lane & 15;
    const int quad = lane >> 4;

    // XCD/L2-friendly decode: id&7 selects image-group (heuristically = XCD via
    // round-robin dispatch); one image's 64 blocks (2.2MB qx + 1.2MB qw < 4MB L2)
    // stay on one XCD; the two o-tiles of a pixel tile are adjacent.
    const int id  = blockIdx.x;              // 0..2047
    const int g   = id >> 3;                 // 0..255
    const int n   = ((g >> 6) << 3) | (id & 7);
    const int j_  = g & 63;
    const int o0  = (j_ & 1) * 128;
    const int hw0 = (j_ >> 1) * 128;
    const int h0  = hw0 >> 6;

    // staging: wave owns 2 slots (16 rows each) of both tiles; 16B per lane
    const int s0 = wave * 2;
    const int r0 = s0 * 16 + (lane >> 2);
    const int r1 = r0 + 16;
    const int co = (lane & 3) * 8;

    const unsigned short* wb0 = qw + (size_t)(o0 + r0) * C_IN + co;
    const unsigned short* wb1 = qw + (size_t)(o0 + r1) * C_IN + co;

    auto xbase = [&](int r) -> const unsigned short* {
        int h = h0 + (r >> 6);
        int w = r & 63;
        return qx + (((size_t)(n*HP + h + 1)) * WP + (w + 1)) * C_IN + co;
    };
    const unsigned short* xb0 = xbase(r0);
    const unsigned short* xb1 = xbase(r1);

    unsigned short* ldsA0 = &Wt[s0*16][0];
    unsigned short* ldsA1 = &Wt[s0*16 + 16][0];
    unsigned short* ldsB0 = &Xt[s0*16][0];
    unsigned short* ldsB1 = &Xt[s0*16 + 16][0];

    const int wmo = (wave & 1) * 64;
    const int wnp = (wave >> 1) * 64;

    f32x4 acc[4][4];
#pragma unroll
    for (int i = 0; i < 4; ++i)
#pragma unroll
        for (int j = 0; j < 4; ++j)
            acc[i][j] = (f32x4){0.f, 0.f, 0.f, 0.f};

    for (int p = 0; p < 9; ++p) {
        const int dh = p/3 - 1, dw = p%3 - 1;
        const int xoff = (dh*WP + dw) * C_IN;
        const int woff = p * (O_OUT * C_IN);
        for (int cc = 0; cc < 8; ++cc) {
            const int c0 = cc * 32;
            gld16(ldsA0, wb0 + woff + c0);
            gld16(ldsA1, wb1 + woff + c0);
            gld16(ldsB0, xb0 + xoff + c0);
            gld16(ldsB1, xb1 + xoff + c0);
            __syncthreads();

            short8 af[4], bf_[4];
#pragma unroll
            for (int i = 0; i < 4; ++i)
                af[i] = *(const short8*)&Wt[wmo + i*16 + lo16][quad*8];
#pragma unroll
            for (int j = 0; j < 4; ++j)
                bf_[j] = *(const short8*)&Xt[wnp + j*16 + lo16][quad*8];
#pragma unroll
            for (int i = 0; i < 4; ++i)
#pragma unroll
                for (int j = 0; j < 4; ++j)
                    acc[i][j] = __builtin_amdgcn_mfma_f32_16x16x32_bf16(
                        af[i], bf_[j], acc[i][j], 0, 0, 0);
            __syncthreads();
        }
    }

#pragma unroll
    for (int i = 0; i < 4; ++i) {
#pragma unroll
        for (int j = 0; j < 4; ++j) {
            int o  = o0 + wmo + i*16 + quad*4;
            int pl = wnp + j*16 + lo16;
            size_t base = ((size_t)(n*O_OUT + o)) * (HH*WW) + hw0 + pl;
#pragma unroll
            for (int r = 0; r < 4; ++r)
                out[base + (size_t)r*(HH*WW)] = acc[i][j][r];
        }
    }
}

extern "C" void kernel_launch(void* const* d_in, const int* in_sizes, int n_in,
                              void* d_out, int out_size, void* d_ws, size_t ws_size,
                              hipStream_t stream) {
    const float* x = (const float*)d_in[0];
    const float* w = (const float*)d_in[1];
    float* out = (float*)d_out;

    unsigned short* qx = (unsigned short*)d_ws;                       // padded NHWC bf16
    unsigned short* qw = (unsigned short*)((char*)d_ws + QX_BYTES);   // [9][O][C] bf16

    halo_zero_kernel<<<dim3(1040), 256, 0, stream>>>(qx);
    quant_x_kernel<<<dim3(N_IMG*HH*4), 256, 0, stream>>>(x, qx);
    quant_w_kernel<<<dim3(O_OUT), 256, 0, stream>>>(w, qw);
    conv_kernel<<<dim3(2048), 256, 0, stream>>>(qw, qx, out);
}